// Round 9
// baseline (303.072 us; speedup 1.0000x reference)
//
#include <hip/hip_runtime.h>
#include <hip/hip_bf16.h>

// C[M,N] = A[M,K] @ B[N,K]^T, fp32 in/out, bf16 MFMA.
// R9: fold the cvt-A pass into the GEMM, on the R8 2-blocks/CU structure.
//   R5/R6 proved the fused A-path functionally correct but it died on the
//   1-block/CU lockstep critical path. R8's regime change (2 independent
//   blocks/CU cover each other's stalls) is the missing prerequisite.
//   A is consumed fp32: 8 float4 reg-loads/thread issued ONE TILE AHEAD
//   (~1500 cyc cover vs ~900 HBM latency), 16 cvt_pk + 4 ds_write_b128
//   into the swizzled layout (linear global chunk tid&7, swizzle at write:
//   slot = chk^(row&7); read side unchanged, verified 0 conflicts).
//   Queue discipline: B(t+1) gload_lds issued BEFORE A(t+2) regs ->
//   boundary s_waitcnt vmcnt(8) drains B, keeps A-regs in flight;
//   lgkmcnt(0) free (ds_writes drain under the 32-MFMA cluster).
//   HBM: -201 MB (cvt-A read+write) +67 MB (A fp32 vs bf16) = -134 net.
// Base (R8, verified 274.8us): BM=128xBN=128/BK=64, 256 thr = 4 waves =
//   2 n-slots x 2 K-halves (0.375 ds_read/MFMA), NBUF=2 ring 64 KiB,
//   grid 512 = 2 blocks/CU, one barrier/tile, cross-wave K-reduction at
//   end, XCD-bijective block swizzle. B via tiny cvt_b (~4us).
//   Abort: e2e>280 or gemm>85 -> revert to R8.

typedef __bf16 bf16x8 __attribute__((ext_vector_type(8)));
typedef float f32x4 __attribute__((ext_vector_type(4)));

#define BM 128
#define BN 128
#define BK 64
// fallback tile
#define TM 128
#define TN 128

#define MFMA16(a_, b_, c_) \
    __builtin_amdgcn_mfma_f32_16x16x32_bf16((a_), (b_), (c_), 0, 0, 0)

__device__ __forceinline__ void load_lds16(const void* g, void* l) {
    __builtin_amdgcn_global_load_lds(
        (const __attribute__((address_space(1))) void*)g,
        (__attribute__((address_space(3))) void*)l,
        16 /*bytes*/, 0 /*offset*/, 0 /*aux*/);
}

// ---- B-only fp32->bf16 convert (A is consumed fp32 by the GEMM).
__global__ void cvt_b(const float* __restrict__ B, uint4* __restrict__ Bo,
                      long n8) {
    const long stride = (long)gridDim.x * blockDim.x;
    for (long i = (long)blockIdx.x * blockDim.x + threadIdx.x; i < n8;
         i += stride) {
        const float4* p = (const float4*)B + i * 2;
        const float4 a = p[0];
        const float4 b = p[1];
        union { __hip_bfloat16 h[8]; uint4 u; } o;
        o.h[0] = __float2bfloat16(a.x); o.h[1] = __float2bfloat16(a.y);
        o.h[2] = __float2bfloat16(a.z); o.h[3] = __float2bfloat16(a.w);
        o.h[4] = __float2bfloat16(b.x); o.h[5] = __float2bfloat16(b.y);
        o.h[6] = __float2bfloat16(b.z); o.h[7] = __float2bfloat16(b.w);
        Bo[i] = o.u;
    }
}

__global__ __launch_bounds__(256, 2) void gemm_bt_pipe(
    const float* __restrict__ Af,  // [M,K] fp32 (converted in-kernel)
    const __bf16* __restrict__ B,  // [N,K] bf16
    float* __restrict__ C,         // [M,N] fp32
    int M, int N, int K) {
    // 64 KiB: 2-buffer ring in the loop, reduction scratch after.
    __shared__ __align__(16) unsigned char smem[65536];
    __bf16* As = (__bf16*)smem;                  // 2 * 128*64*2 = 32 KiB
    __bf16* Bs = (__bf16*)(smem + 32768);        // 2 * 128*64*2 = 32 KiB

    const int tid = threadIdx.x;
    const int wave = tid >> 6;
    const int lane = tid & 63;

    // ---- XCD-bijective swizzle: XCD x owns an 8bm x 8bn chunk.
    const int nbn = N / BN;               // 8
    const int nbm = M / BM;               // 64
    const int L = (int)blockIdx.x;
    int bm, bn;
    if ((nbm & 7) == 0) {
        const int x = L & 7;
        const int s = L >> 3;
        bm = x * (nbm >> 3) + s / nbn;
        bn = s % nbn;
    } else {
        bm = L / nbn;
        bn = L % nbn;
    }

    // ---- staging: row = 8 chunks of 16B(bf16); 256 thr = 32 rows/round.
    const int srow = tid >> 3;                    // row within round (0..31)
    const int chk = tid & 7;                      // linear chunk (global side)
    const int schk = chk ^ (srow & 7);            // swizzled LDS slot
    // A fp32: LINEAR global read; swizzle applied at ds_write.
    const float* ga32 = Af + ((size_t)bm * BM + srow) * (size_t)K + chk * 8;
    // B bf16: pre-swizzled global fetch feeds gload_lds's linear placement.
    const __bf16* gb = B + ((size_t)bn * BN + srow) * (size_t)K + schk * 8;
    const size_t g32 = (size_t)32 * K;            // 32-row advance per round
    const int ldst = tid * 8;                     // B LDS elem offset/round
    const int lasw = srow * 64 + schk * 8;        // A LDS elem offset/round

    // ---- fragment addressing: n-slot ws = wave&1 -> 128x64 tile at
    // (0, ws*64); K-half wk = wave>>1 -> chunks 4wk..4wk+3.
    const int ws = wave & 1;
    const int wk = wave >> 1;
    const int wn = ws << 6;           // 0,64
    const int fr = lane & 15;
    const int qd = lane >> 4;
    const int r7 = fr & 7;
    const int sl = ((qd + 4 * wk) ^ r7) << 3;     // swizzled 16B slot

    f32x4 acc[8][4];
#pragma unroll
    for (int i = 0; i < 8; ++i)
#pragma unroll
        for (int j = 0; j < 4; ++j) acc[i][j] = (f32x4){0.f, 0.f, 0.f, 0.f};

    const int NT = K / BK;  // 64

    float4 areg[8];
#define ISSUE_A(kc)                                                           \
    do {                                                                      \
        _Pragma("unroll") for (int r = 0; r < 4; ++r) {                       \
            const float* p_ = ga32 + r * g32 + (kc);                          \
            areg[2 * r] = *(const float4*)p_;                                 \
            areg[2 * r + 1] = *(const float4*)(p_ + 4);                       \
        }                                                                     \
    } while (0)
#define CVT_WRITE_A(dst_)                                                     \
    do {                                                                      \
        _Pragma("unroll") for (int r = 0; r < 4; ++r) {                       \
            union { __hip_bfloat162 h2[4]; uint4 u; } o_;                     \
            o_.h2[0] = __float22bfloat162_rn(                                 \
                make_float2(areg[2 * r].x, areg[2 * r].y));                   \
            o_.h2[1] = __float22bfloat162_rn(                                 \
                make_float2(areg[2 * r].z, areg[2 * r].w));                   \
            o_.h2[2] = __float22bfloat162_rn(                                 \
                make_float2(areg[2 * r + 1].x, areg[2 * r + 1].y));           \
            o_.h2[3] = __float22bfloat162_rn(                                 \
                make_float2(areg[2 * r + 1].z, areg[2 * r + 1].w));           \
            *(uint4*)((dst_) + r * 2048 + lasw) = o_.u;                       \
        }                                                                     \
    } while (0)

    // ---- prologue: A(0) regs -> cvt -> As0; B(0) gloads; A(1) regs issued
    // AFTER B(0) so vmcnt(8) drains B(0) and keeps A(1) in flight.
    ISSUE_A(0);
    CVT_WRITE_A(As);                       // compiler places the A(0) wait
#pragma unroll
    for (int r = 0; r < 4; ++r) load_lds16(gb + r * g32, Bs + ldst + r * 2048);
    ISSUE_A(BK);
    asm volatile("s_waitcnt vmcnt(8) lgkmcnt(0)" ::: "memory");
    __builtin_amdgcn_s_barrier();
    asm volatile("" ::: "memory");

    int cur = 0;
    for (int t = 0; t < NT; ++t) {
        const __bf16* as = As + cur * (BM * BK);
        const __bf16* bs = Bs + cur * (BN * BK);
        __bf16* asw = As + (cur ^ 1) * (BM * BK);
        __bf16* bsw = Bs + (cur ^ 1) * (BN * BK);

        // ---- fragment reads: 12 ds_read_b128
        bf16x8 af[8], bf[4];
#pragma unroll
        for (int j = 0; j < 4; ++j)
            bf[j] = *(const bf16x8*)(bs + (wn + j * 16 + fr) * BK + sl);
#pragma unroll
        for (int i = 0; i < 8; ++i)
            af[i] = *(const bf16x8*)(as + (i * 16 + fr) * BK + sl);

        // ---- stage tile t+1: cvt A(t+1) from regs (issued at t-1, one
        // full tile of latency cover) + swizzled ds_write; B(t+1) gloads;
        // then re-issue A(t+2) regs. Writes drain under the MFMA cluster.
        if (t + 1 < NT) {
            const size_t kg = (size_t)(t + 1) * BK;
            CVT_WRITE_A(asw);
#pragma unroll
            for (int r = 0; r < 4; ++r)
                load_lds16(gb + r * g32 + kg, bsw + ldst + r * 2048);
            if (t + 2 < NT) ISSUE_A((size_t)(t + 2) * BK);
        }

        // ---- single 32-MFMA cluster (K-half wk)
        __builtin_amdgcn_s_setprio(1);
#pragma unroll
        for (int i = 0; i < 8; ++i)
#pragma unroll
            for (int j = 0; j < 4; ++j)
                acc[i][j] = MFMA16(af[i], bf[j], acc[i][j]);
        __builtin_amdgcn_s_setprio(0);

        // ---- boundary: drain B(t+1) (vmcnt(8) keeps A(t+2)x8 in flight),
        // publish ds_writes (lgkm already drained under MFMA), barrier.
        if (t + 1 < NT) {
            if (t + 2 < NT)
                asm volatile("s_waitcnt vmcnt(8) lgkmcnt(0)" ::: "memory");
            else
                asm volatile("s_waitcnt vmcnt(0) lgkmcnt(0)" ::: "memory");
            __builtin_amdgcn_s_barrier();
            asm volatile("" ::: "memory");
        }
        cur ^= 1;
    }

    // ---- cross-wave K-reduction: wk=1 waves dump acc, wk=0 partners add.
    float* red = (float*)smem;
    __syncthreads();
    if (wk == 1) {
        float* dst = red + ws * 8192;
#pragma unroll
        for (int i = 0; i < 8; ++i)
#pragma unroll
            for (int j = 0; j < 4; ++j)
                *(f32x4*)(dst + (i * 4 + j) * 256 + lane * 4) = acc[i][j];
    }
    __syncthreads();
    if (wk == 0) {
        const float* src = red + ws * 8192;
#pragma unroll
        for (int i = 0; i < 8; ++i)
#pragma unroll
            for (int j = 0; j < 4; ++j) {
                f32x4 v = *(const f32x4*)(src + (i * 4 + j) * 256 + lane * 4);
                acc[i][j] += v;
            }

        // ---- epilogue: C/D layout col=lane&15, row=(lane>>4)*4+reg
        const int cq = qd << 2;
        float* Cbase = C + ((size_t)bm * BM + cq) * (size_t)N +
                       (size_t)bn * BN + wn + fr;
#pragma unroll
        for (int i = 0; i < 8; ++i)
#pragma unroll
            for (int r = 0; r < 4; ++r) {
                float* row = Cbase + (size_t)(16 * i + r) * N;
#pragma unroll
                for (int j = 0; j < 4; ++j) row[16 * j] = acc[i][j][r];
            }
    }
}

// Fallback if ws too small: fused-convert GEMM (BK=32), plain stores.
__global__ __launch_bounds__(256, 2) void gemm_bt_f32in(
    const float* __restrict__ A, const float* __restrict__ B,
    float* __restrict__ C, int M, int N, int K) {
    __shared__ __bf16 As[TM * 32];
    __shared__ __bf16 Bs[TN * 32];

    const int tid = threadIdx.x;
    const int wave = tid >> 6;
    const int lane = tid & 63;
    const int bn = blockIdx.x;
    const int bm = blockIdx.y;

    const int frow = tid >> 3;
    const int fcol = (tid & 7) << 2;
    const float* gaf = A + ((size_t)bm * TM + frow) * (size_t)K + fcol;
    const float* gbf = B + ((size_t)bn * TN + frow) * (size_t)K + fcol;

    const int wm = (wave >> 1) << 6;
    const int wn = (wave & 1) << 6;
    const int fr = lane & 15;
    const int fk = (lane >> 4) << 3;
    const __bf16* pa = As + (wm + fr) * 32 + fk;
    const __bf16* pb = Bs + (wn + fr) * 32 + fk;

    f32x4 acc[4][4];
#pragma unroll
    for (int i = 0; i < 4; ++i)
#pragma unroll
        for (int j = 0; j < 4; ++j) acc[i][j] = (f32x4){0.f, 0.f, 0.f, 0.f};

    for (int k0 = 0; k0 < K; k0 += 32) {
#pragma unroll
        for (int rd = 0; rd < 4; ++rd) {
            float4 va = *(const float4*)(gaf + (size_t)(rd * 32) * K + k0);
            float4 vb = *(const float4*)(gbf + (size_t)(rd * 32) * K + k0);
            union { __hip_bfloat162 h2[2]; uint2 u; } oa, ob;
            oa.h2[0] = __float22bfloat162_rn(make_float2(va.x, va.y));
            oa.h2[1] = __float22bfloat162_rn(make_float2(va.z, va.w));
            ob.h2[0] = __float22bfloat162_rn(make_float2(vb.x, vb.y));
            ob.h2[1] = __float22bfloat162_rn(make_float2(vb.z, vb.w));
            *(uint2*)(As + (frow + rd * 32) * 32 + fcol) = oa.u;
            *(uint2*)(Bs + (frow + rd * 32) * 32 + fcol) = ob.u;
        }
        __syncthreads();

        bf16x8 af[4], bfr[4];
#pragma unroll
        for (int i = 0; i < 4; ++i) af[i] = *(const bf16x8*)(pa + i * (16 * 32));
#pragma unroll
        for (int j = 0; j < 4; ++j) bfr[j] = *(const bf16x8*)(pb + j * (16 * 32));
#pragma unroll
        for (int i = 0; i < 4; ++i)
#pragma unroll
            for (int j = 0; j < 4; ++j)
                acc[i][j] = __builtin_amdgcn_mfma_f32_16x16x32_bf16(
                    af[i], bfr[j], acc[i][j], 0, 0, 0);
        __syncthreads();
    }

    const int cq = (lane >> 4) << 2;
    float* Cbase = C + ((size_t)bm * TM + wm + cq) * (size_t)N +
                   (size_t)bn * TN + wn + fr;
#pragma unroll
    for (int i = 0; i < 4; ++i)
#pragma unroll
        for (int r = 0; r < 4; ++r) {
            float* row = Cbase + (size_t)(16 * i + r) * N;
#pragma unroll
            for (int j = 0; j < 4; ++j) row[16 * j] = acc[i][j][r];
        }
}

extern "C" void kernel_launch(void* const* d_in, const int* in_sizes, int n_in,
                              void* d_out, int out_size, void* d_ws,
                              size_t ws_size, hipStream_t stream) {
    const float* A = (const float*)d_in[0];  // [M,K] (all_gather = reshape)
    const float* B = (const float*)d_in[1];  // [N,K]
    float* C = (float*)d_out;

    const int K = 4096;
    const int aN = in_sizes[0];
    const int bN = in_sizes[1];
    const int M = aN / K;  // 8192
    const int N = bN / K;  // 1024

    const size_t need = (size_t)bN * sizeof(__hip_bfloat16);  // B only

    if (ws_size >= need && (M % BM) == 0 && (N % BN) == 0 && K >= 3 * BK) {
        __hip_bfloat16* Bbf = (__hip_bfloat16*)d_ws;
        cvt_b<<<(unsigned)((bN / 8 + 255) / 256), 256, 0, stream>>>(
            B, (uint4*)Bbf, (long)(bN / 8));
        dim3 grid((unsigned)((M / BM) * (N / BN)));  // 512 = 2 blocks/CU
        gemm_bt_pipe<<<grid, 256, 0, stream>>>(A, (const __bf16*)Bbf, C, M, N,
                                               K);
    } else {
        dim3 grid(N / TN, M / TM);
        gemm_bt_f32in<<<grid, 256, 0, stream>>>(A, B, C, M, N, K);
    }
}

// Round 10
// 277.158 us; speedup vs baseline: 1.0935x; 1.0935x over previous
//
#include <hip/hip_runtime.h>
#include <hip/hip_bf16.h>

// C[M,N] = A[M,K] @ B[N,K]^T, fp32 in/out, bf16 MFMA.
// R10 = R8 (verified 274.8us) + A-ring depth-2. Fusion of cvt-A is dead
//   (R5/R6/R9 all regressed: the areg-wait+cvt+ds_write chain sits on the
//   per-tile critical path and can't be fire-and-forget). cvt_all stays
//   (36us, HBM-ceiling). The one exposed stall left in R8 was the boundary
//   vmcnt(0) draining same-tile-issued loads (~620 cyc cover vs ~900 HBM
//   first-touch for A). Fix: A 3-buffer ring (depth-2 prefetch), B ring 2;
//   LDS 48+32 = 80 KiB = exactly 2 blocks/CU. Per tile: issue B(t+1) THEN
//   A(t+2); boundary s_waitcnt vmcnt(4) drains A(t+1) (2 tiles old, free)
//   + B(t+1) (unchanged), keeps A(t+2)x4 in flight ACROSS the barrier
//   (counted vmcnt, never 0 until tail). Ring safety: A slot (t+2)%3 last
//   read at t-1, published by the t-1 boundary barrier.
// Base: BM=128xBN=128/BK=64, 256 thr = 4 waves = 2 n-slots x 2 K-halves
//   (12 ds_read_b128 per 32 MFMA), grid 512 = 2 blocks/CU (independent
//   barrier domains cover each other's stalls — R8's proven win),
//   cross-wave K-reduction at end, XOR bank-swizzle (0 conflicts),
//   XCD-bijective block swizzle (fetch = compulsory ~65 MB).

typedef __bf16 bf16x8 __attribute__((ext_vector_type(8)));
typedef float f32x4 __attribute__((ext_vector_type(4)));

#define BM 128
#define BN 128
#define BK 64
// fallback tile
#define TM 128
#define TN 128

#define MFMA16(a_, b_, c_) \
    __builtin_amdgcn_mfma_f32_16x16x32_bf16((a_), (b_), (c_), 0, 0, 0)

__device__ __forceinline__ void load_lds16(const void* g, void* l) {
    __builtin_amdgcn_global_load_lds(
        (const __attribute__((address_space(1))) void*)g,
        (__attribute__((address_space(3))) void*)l,
        16 /*bytes*/, 0 /*offset*/, 0 /*aux*/);
}

// ---- fused convert: A then B, grid-stride.
__global__ void cvt_all(const float* __restrict__ A, uint4* __restrict__ Ao,
                        long nA8, const float* __restrict__ B,
                        uint4* __restrict__ Bo, long nB8) {
    const long stride = (long)gridDim.x * blockDim.x;
    const long tot = nA8 + nB8;
    for (long i = (long)blockIdx.x * blockDim.x + threadIdx.x; i < tot;
         i += stride) {
        const float4* p;
        uint4* d;
        if (i < nA8) {
            p = (const float4*)A + i * 2;
            d = Ao + i;
        } else {
            const long j = i - nA8;
            p = (const float4*)B + j * 2;
            d = Bo + j;
        }
        const float4 a = p[0];
        const float4 b = p[1];
        union { __hip_bfloat16 h[8]; uint4 u; } o;
        o.h[0] = __float2bfloat16(a.x); o.h[1] = __float2bfloat16(a.y);
        o.h[2] = __float2bfloat16(a.z); o.h[3] = __float2bfloat16(a.w);
        o.h[4] = __float2bfloat16(b.x); o.h[5] = __float2bfloat16(b.y);
        o.h[6] = __float2bfloat16(b.z); o.h[7] = __float2bfloat16(b.w);
        *d = o.u;
    }
}

__global__ __launch_bounds__(256, 2) void gemm_bt_pipe(
    const __bf16* __restrict__ A,  // [M,K] bf16
    const __bf16* __restrict__ B,  // [N,K] bf16
    float* __restrict__ C,         // [M,N] fp32
    int M, int N, int K) {
    // 80 KiB: A ring 3 x 16 KiB, B ring 2 x 16 KiB; reduction reuses.
    __shared__ __align__(16) unsigned char smem[81920];
    __bf16* As = (__bf16*)smem;                  // 3 * 128*64*2 = 48 KiB
    __bf16* Bs = (__bf16*)(smem + 49152);        // 2 * 128*64*2 = 32 KiB

    const int tid = threadIdx.x;
    const int wave = tid >> 6;
    const int lane = tid & 63;

    // ---- XCD-bijective swizzle: XCD x owns an 8bm x 8bn chunk.
    const int nbn = N / BN;               // 8
    const int nbm = M / BM;               // 64
    const int L = (int)blockIdx.x;
    int bm, bn;
    if ((nbm & 7) == 0) {
        const int x = L & 7;
        const int s = L >> 3;
        bm = x * (nbm >> 3) + s / nbn;
        bn = s % nbn;
    } else {
        bm = L / nbn;
        bn = L % nbn;
    }

    // ---- staging: row = 128 B = 8 chunks; 256 threads cover 32 rows/round.
    // A tile = 4 rounds, B tile = 4 rounds.
    const int srow = tid >> 3;                    // row within round (0..31)
    const int schk = (tid & 7) ^ (srow & 7);      // pre-swizzled global chunk
    const __bf16* ga = A + ((size_t)bm * BM + srow) * (size_t)K + schk * 8;
    const __bf16* gb = B + ((size_t)bn * BN + srow) * (size_t)K + schk * 8;
    const size_t g32 = (size_t)32 * K;            // 32-row advance per round
    const int ldst = tid * 8;                     // LDS elem offset in round

    // ---- fragment addressing: n-slot ws = wave&1 -> 128x64 tile at
    // (0, ws*64); K-half wk = wave>>1 -> chunks 4wk..4wk+3.
    const int ws = wave & 1;
    const int wk = wave >> 1;
    const int wn = ws << 6;           // 0,64
    const int fr = lane & 15;
    const int qd = lane >> 4;
    const int r7 = fr & 7;
    const int sl = ((qd + 4 * wk) ^ r7) << 3;     // swizzled 16B slot

    f32x4 acc[8][4];
#pragma unroll
    for (int i = 0; i < 8; ++i)
#pragma unroll
        for (int j = 0; j < 4; ++j) acc[i][j] = (f32x4){0.f, 0.f, 0.f, 0.f};

    const int NT = K / BK;  // 64 (launcher guarantees NT >= 4)

    // ---- prologue: A(0), B(0), A(1) in that order -> vmcnt(4) drains
    // A(0)+B(0), leaves A(1)x4 in flight (steady-state queue shape).
#pragma unroll
    for (int r = 0; r < 4; ++r) load_lds16(ga + r * g32, As + ldst + r * 2048);
#pragma unroll
    for (int r = 0; r < 4; ++r) load_lds16(gb + r * g32, Bs + ldst + r * 2048);
    asm volatile("" ::: "memory");
#pragma unroll
    for (int r = 0; r < 4; ++r)
        load_lds16(ga + r * g32 + BK, As + 8192 + ldst + r * 2048);
    asm volatile("s_waitcnt vmcnt(4)" ::: "memory");
    __builtin_amdgcn_s_barrier();
    asm volatile("" ::: "memory");

    int ca = 0, cb = 0;  // A slot t%3, B slot t%2
    for (int t = 0; t < NT; ++t) {
        const __bf16* as = As + ca * 8192;
        const __bf16* bs = Bs + cb * 8192;

        // ---- fragment reads: 12 ds_read_b128
        bf16x8 af[8], bf[4];
#pragma unroll
        for (int j = 0; j < 4; ++j)
            bf[j] = *(const bf16x8*)(bs + (wn + j * 16 + fr) * BK + sl);
#pragma unroll
        for (int i = 0; i < 8; ++i)
            af[i] = *(const bf16x8*)(as + (i * 16 + fr) * BK + sl);

        // ---- issue B(t+1) into slot cb^1 (last read at t-1), THEN
        // A(t+2) into slot (ca+2)%3 (last read at t-1) -> boundary
        // vmcnt(4) keeps A(t+2) in flight.
        if (t + 1 < NT) {
            const size_t kg1 = (size_t)(t + 1) * BK;
            __bf16* bsw = Bs + (cb ^ 1) * 8192;
#pragma unroll
            for (int r = 0; r < 4; ++r)
                load_lds16(gb + r * g32 + kg1, bsw + ldst + r * 2048);
        }
        if (t + 2 < NT) {
            const size_t kg2 = (size_t)(t + 2) * BK;
            __bf16* asw = As + ((ca + 2) % 3) * 8192;
#pragma unroll
            for (int r = 0; r < 4; ++r)
                load_lds16(ga + r * g32 + kg2, asw + ldst + r * 2048);
        }

        // ---- single 32-MFMA cluster (K-half wk); staging flies under.
        __builtin_amdgcn_s_setprio(1);
#pragma unroll
        for (int i = 0; i < 8; ++i)
#pragma unroll
            for (int j = 0; j < 4; ++j)
                acc[i][j] = MFMA16(af[i], bf[j], acc[i][j]);
        __builtin_amdgcn_s_setprio(0);

        // ---- boundary: counted drain (A(t+1) is 2 tiles old = free;
        // B(t+1) same exposure as R8), barrier publishes, A(t+2) stays
        // in flight across it. Tail drains to 0.
        if (t + 1 < NT) {
            if (t + 2 < NT)
                asm volatile("s_waitcnt vmcnt(4)" ::: "memory");
            else
                asm volatile("s_waitcnt vmcnt(0)" ::: "memory");
            __builtin_amdgcn_s_barrier();
            asm volatile("" ::: "memory");
        }
        ca = (ca == 2) ? 0 : ca + 1;
        cb ^= 1;
    }

    // ---- cross-wave K-reduction: wk=1 waves dump acc, wk=0 partners add.
    // Scratch: 2 slots x 32 KiB = 64 KiB <= 80 KiB (ring reuse).
    float* red = (float*)smem;
    __syncthreads();
    if (wk == 1) {
        float* dst = red + ws * 8192;
#pragma unroll
        for (int i = 0; i < 8; ++i)
#pragma unroll
            for (int j = 0; j < 4; ++j)
                *(f32x4*)(dst + (i * 4 + j) * 256 + lane * 4) = acc[i][j];
    }
    __syncthreads();
    if (wk == 0) {
        const float* src = red + ws * 8192;
#pragma unroll
        for (int i = 0; i < 8; ++i)
#pragma unroll
            for (int j = 0; j < 4; ++j) {
                f32x4 v = *(const f32x4*)(src + (i * 4 + j) * 256 + lane * 4);
                acc[i][j] += v;
            }

        // ---- epilogue: C/D layout col=lane&15, row=(lane>>4)*4+reg
        const int cq = qd << 2;
        float* Cbase = C + ((size_t)bm * BM + cq) * (size_t)N +
                       (size_t)bn * BN + wn + fr;
#pragma unroll
        for (int i = 0; i < 8; ++i)
#pragma unroll
            for (int r = 0; r < 4; ++r) {
                float* row = Cbase + (size_t)(16 * i + r) * N;
#pragma unroll
                for (int j = 0; j < 4; ++j) row[16 * j] = acc[i][j][r];
            }
    }
}

// Fallback if ws too small: fused-convert GEMM (BK=32), plain stores.
__global__ __launch_bounds__(256, 2) void gemm_bt_f32in(
    const float* __restrict__ A, const float* __restrict__ B,
    float* __restrict__ C, int M, int N, int K) {
    __shared__ __bf16 As[TM * 32];
    __shared__ __bf16 Bs[TN * 32];

    const int tid = threadIdx.x;
    const int wave = tid >> 6;
    const int lane = tid & 63;
    const int bn = blockIdx.x;
    const int bm = blockIdx.y;

    const int frow = tid >> 3;
    const int fcol = (tid & 7) << 2;
    const float* gaf = A + ((size_t)bm * TM + frow) * (size_t)K + fcol;
    const float* gbf = B + ((size_t)bn * TN + frow) * (size_t)K + fcol;

    const int wm = (wave >> 1) << 6;
    const int wn = (wave & 1) << 6;
    const int fr = lane & 15;
    const int fk = (lane >> 4) << 3;
    const __bf16* pa = As + (wm + fr) * 32 + fk;
    const __bf16* pb = Bs + (wn + fr) * 32 + fk;

    f32x4 acc[4][4];
#pragma unroll
    for (int i = 0; i < 4; ++i)
#pragma unroll
        for (int j = 0; j < 4; ++j) acc[i][j] = (f32x4){0.f, 0.f, 0.f, 0.f};

    for (int k0 = 0; k0 < K; k0 += 32) {
#pragma unroll
        for (int rd = 0; rd < 4; ++rd) {
            float4 va = *(const float4*)(gaf + (size_t)(rd * 32) * K + k0);
            float4 vb = *(const float4*)(gbf + (size_t)(rd * 32) * K + k0);
            union { __hip_bfloat162 h2[2]; uint2 u; } oa, ob;
            oa.h2[0] = __float22bfloat162_rn(make_float2(va.x, va.y));
            oa.h2[1] = __float22bfloat162_rn(make_float2(va.z, va.w));
            ob.h2[0] = __float22bfloat162_rn(make_float2(vb.x, vb.y));
            ob.h2[1] = __float22bfloat162_rn(make_float2(vb.z, vb.w));
            *(uint2*)(As + (frow + rd * 32) * 32 + fcol) = oa.u;
            *(uint2*)(Bs + (frow + rd * 32) * 32 + fcol) = ob.u;
        }
        __syncthreads();

        bf16x8 af[4], bfr[4];
#pragma unroll
        for (int i = 0; i < 4; ++i) af[i] = *(const bf16x8*)(pa + i * (16 * 32));
#pragma unroll
        for (int j = 0; j < 4; ++j) bfr[j] = *(const bf16x8*)(pb + j * (16 * 32));
#pragma unroll
        for (int i = 0; i < 4; ++i)
#pragma unroll
            for (int j = 0; j < 4; ++j)
                acc[i][j] = __builtin_amdgcn_mfma_f32_16x16x32_bf16(
                    af[i], bfr[j], acc[i][j], 0, 0, 0);
        __syncthreads();
    }

    const int cq = (lane >> 4) << 2;
    float* Cbase = C + ((size_t)bm * TM + wm + cq) * (size_t)N +
                   (size_t)bn * TN + wn + fr;
#pragma unroll
    for (int i = 0; i < 4; ++i)
#pragma unroll
        for (int r = 0; r < 4; ++r) {
            float* row = Cbase + (size_t)(16 * i + r) * N;
#pragma unroll
            for (int j = 0; j < 4; ++j) row[16 * j] = acc[i][j][r];
        }
}

extern "C" void kernel_launch(void* const* d_in, const int* in_sizes, int n_in,
                              void* d_out, int out_size, void* d_ws,
                              size_t ws_size, hipStream_t stream) {
    const float* A = (const float*)d_in[0];  // [M,K] (all_gather = reshape)
    const float* B = (const float*)d_in[1];  // [N,K]
    float* C = (float*)d_out;

    const int K = 4096;
    const int aN = in_sizes[0];
    const int bN = in_sizes[1];
    const int M = aN / K;  // 8192
    const int N = bN / K;  // 1024

    const size_t need = ((size_t)aN + (size_t)bN) * sizeof(__hip_bfloat16);

    if (ws_size >= need && (M % BM) == 0 && (N % BN) == 0 && K >= 4 * BK) {
        __hip_bfloat16* Abf = (__hip_bfloat16*)d_ws;
        __hip_bfloat16* Bbf = Abf + (size_t)aN;
        cvt_all<<<2048, 256, 0, stream>>>(A, (uint4*)Abf, (long)(aN / 8), B,
                                          (uint4*)Bbf, (long)(bN / 8));
        dim3 grid((unsigned)((M / BM) * (N / BN)));  // 512 = 2 blocks/CU
        gemm_bt_pipe<<<grid, 256, 0, stream>>>((const __bf16*)Abf,
                                               (const __bf16*)Bbf, C, M, N, K);
    } else {
        dim3 grid(N / TN, M / TM);
        gemm_bt_f32in<<<grid, 256, 0, stream>>>(A, B, C, M, N, K);
    }
}